// Round 7
// baseline (11519.473 us; speedup 1.0000x reference)
//
#include <hip/hip_runtime.h>
#include <cstddef>

#define Bn  256
#define Tn  1024
#define Cn  128
#define Hn  256
#define WIN 24

#define NRG 16
#define NUG 16
#define RPB 16
#define UPB 16

#define AGENT __HIP_MEMORY_SCOPE_AGENT
#define RLX   __ATOMIC_RELAXED

typedef __attribute__((ext_vector_type(8))) short bf16x8;
typedef __attribute__((ext_vector_type(4))) float f32x4;

#define MFMA(a, b, c) __builtin_amdgcn_mfma_f32_16x16x32_bf16((a), (b), (c), 0, 0, 0)

// h_in exchange: packed {tag (hi32), value bits (lo32)}, double-buffered by parity.
__device__ unsigned long long g_hxp[2][Bn][Hn];

__device__ inline unsigned short f2bf(float f) {
    union { float f; unsigned u; } v; v.f = f;
    unsigned r = (v.u + 0x7FFF + ((v.u >> 16) & 1)) >> 16;   // RNE
    return (unsigned short)r;
}
__device__ inline float bf2f(unsigned short b) {
    union { unsigned u; float f; } v; v.u = (unsigned)b << 16;
    return v.f;
}
__device__ inline void split8(const float* s, bf16x8& hi, bf16x8& lo) {
    #pragma unroll
    for (int e = 0; e < 8; ++e) {
        unsigned short h = f2bf(s[e]);
        float r = s[e] - bf2f(h);
        hi[e] = (short)h;
        lo[e] = (short)f2bf(r);
    }
}
__device__ inline float pk_val(unsigned long long p) {
    union { unsigned u; float f; } v; v.u = (unsigned)(p & 0xffffffffu);
    return v.f;
}
__device__ inline unsigned long long pk_make(int tag, float f) {
    union { float f; unsigned u; } v; v.f = f;
    return ((unsigned long long)(unsigned)tag << 32) | (unsigned long long)v.u;
}

__global__ __launch_bounds__(256) void init_pack(const float* __restrict__ h0) {
    int i = blockIdx.x * 256 + threadIdx.x;        // 0 .. 65535 = [b][u]
    g_hxp[0][i >> 8][i & 255] = pk_make(0, h0[i & 255]);  // h_in(0)=h0, tag 0
    g_hxp[1][i >> 8][i & 255] = pk_make(0, 0.f);          // tag 0 < 1: poll at t=1
}

__global__ __launch_bounds__(512, 1) void lstm_persist(
    const float* __restrict__ x,
    const float* __restrict__ W_ih, const float* __restrict__ W_hh,
    const float* __restrict__ b_ih, const float* __restrict__ b_hh,
    const float* __restrict__ W_skip, const float* __restrict__ b_skip,
    const float* __restrict__ c0,
    float* __restrict__ outp, float* __restrict__ hbuf, float* __restrict__ cbuf)
{
    extern __shared__ char s_dynpad[];    // pad: LDS > 80KB -> exactly 1 block/CU
    (void)s_dynpad;

    __shared__ bf16x8 s_ga[2][12][64];
    __shared__ bf16x8 s_sa[2][8][64];
    __shared__ float  s_part[2][4][64][4];
    __shared__ float  s_sk[8][64][4];
    __shared__ float  s_hown[16][16];
    __shared__ float  s_bias[64];
    __shared__ float  s_bskip[UPB];

    const int tid = threadIdx.x;
    const int xcd = blockIdx.x & 7, slot = blockIdx.x >> 3;
    const int rg = (xcd << 1) | (slot >> 4), ug = slot & 15;
    const int row0 = rg * RPB, u0 = ug * UPB;

    const int w    = tid >> 6;
    const int lane = tid & 63;
    const int g    = w & 3;
    const int kh   = w >> 2;
    const int nl   = lane & 15;
    const int kq   = lane >> 4;

    const int sm   = lane & 15;
    const int kq2  = lane >> 4;
    const int k0   = w * 32 + kq2 * 8;
    const bool own = (k0 >> 4) == ug;

    bf16x8 whh_hi[4], whh_lo[4], wx_hi[2], wx_lo[2], ws_hi, ws_lo;
    {
        const int Rg = g * Hn + u0 + nl;
        const float* wr = W_hh + (size_t)Rg * Hn;
        #pragma unroll
        for (int j = 0; j < 4; ++j) {
            float tmp[8];
            const int k = (kh * 4 + j) * 32 + kq * 8;
            #pragma unroll
            for (int e = 0; e < 8; ++e) tmp[e] = wr[k + e];
            split8(tmp, whh_hi[j], whh_lo[j]);
        }
        const float* wr2 = W_ih + (size_t)Rg * Cn;
        #pragma unroll
        for (int j = 0; j < 2; ++j) {
            float tmp[8];
            const int k = (kh * 2 + j) * 32 + kq * 8;
            #pragma unroll
            for (int e = 0; e < 8; ++e) tmp[e] = wr2[k + e];
            split8(tmp, wx_hi[j], wx_lo[j]);
        }
        const float* wr3 = W_skip + (size_t)(u0 + nl) * Hn;
        float tmp[8];
        const int k = w * 32 + kq * 8;
        #pragma unroll
        for (int e = 0; e < 8; ++e) tmp[e] = wr3[k + e];
        split8(tmp, ws_hi, ws_lo);
    }
    if (tid < 64)  s_bias[tid]  = b_ih[(tid >> 4) * Hn + u0 + (tid & 15)]
                                + b_hh[(tid >> 4) * Hn + u0 + (tid & 15)];
    if (tid < 16)  s_bskip[tid] = b_skip[u0 + tid];

    float c_reg = 0.f;
    if (tid < 256) c_reg = c0[u0 + (tid & 15)];
    if (tid < 256) {
        unsigned long long p = g_hxp[0][row0 + (tid >> 4)][u0 + (tid & 15)];
        s_hown[tid >> 4][tid & 15] = pk_val(p);
    }

    float rv[8];
    #pragma unroll
    for (int e = 0; e < 8; ++e) rv[e] = 0.f;
    __syncthreads();

    for (int t = 0; t < Tn; ++t) {
        const bool do_ring = (t >= WIN - 1) && (t < Tn - 1);
        const bool nr      = (t + 1 >= WIN - 1) && (t + 1 < Tn - 1);

        // ---- PHASE A ----
        unsigned long long pv[8];
        const unsigned long long* hsp = &g_hxp[t & 1][row0 + sm][k0];
        if (!own) {
            #pragma unroll
            for (int e = 0; e < 8; ++e)
                pv[e] = __hip_atomic_load((unsigned long long*)&hsp[e], RLX, AGENT);
        }

        if (tid < 256) {
            const int ksx = tid >> 6, lx = tid & 63;
            const int mx = lx & 15, kqx = lx >> 4;
            const float* src = x + (size_t)(row0 + mx) * (Tn * Cn) + (size_t)t * Cn
                                 + ksx * 32 + kqx * 8;
            float tmp[8];
            #pragma unroll
            for (int e = 0; e < 8; ++e) tmp[e] = src[e];
            bf16x8 hi, lo; split8(tmp, hi, lo);
            s_ga[0][ksx][lx] = hi; s_ga[1][ksx][lx] = lo;
        }

        if (do_ring) {
            bf16x8 hi, lo; split8(rv, hi, lo);
            s_sa[0][w][lane] = hi; s_sa[1][w][lane] = lo;
        }

        if (nr) {
            const float* hsrc = outp + (size_t)(row0 + sm) * (Tn * Hn)
                                     + (size_t)(t + 1 - (WIN - 1)) * Hn + k0;
            #pragma unroll
            for (int e = 0; e < 8; ++e)
                rv[e] = __hip_atomic_load((float*)&hsrc[e], RLX, AGENT);
        }
        __syncthreads();   // (1)

        f32x4 ac0 = {0.f,0.f,0.f,0.f}, ac1 = {0.f,0.f,0.f,0.f}, ac2 = {0.f,0.f,0.f,0.f};
        #pragma unroll
        for (int j = 0; j < 2; ++j) {
            const int ks = kh * 2 + j;
            bf16x8 ah = s_ga[0][ks][lane], al = s_ga[1][ks][lane];
            ac0 = MFMA(ah, wx_hi[j], ac0);
            ac1 = MFMA(ah, wx_lo[j], ac1);
            ac2 = MFMA(al, wx_hi[j], ac2);
        }
        if (do_ring) {
            f32x4 k0a = {0.f,0.f,0.f,0.f}, k1a = {0.f,0.f,0.f,0.f}, k2a = {0.f,0.f,0.f,0.f};
            bf16x8 ah = s_sa[0][w][lane], al = s_sa[1][w][lane];
            k0a = MFMA(ah, ws_hi, k0a);
            k1a = MFMA(ah, ws_lo, k1a);
            k2a = MFMA(al, ws_hi, k2a);
            *(f32x4*)&s_sk[w][lane][0] = k0a + k1a + k2a;
        }

        // ---- PHASE B ----
        float tmph[8];
        if (own) {
            #pragma unroll
            for (int e = 0; e < 8; ++e) tmph[e] = s_hown[sm][(k0 & 15) + e];
        } else {
            while (true) {
                unsigned need = 0;
                #pragma unroll
                for (int e = 0; e < 8; ++e)
                    if ((int)(pv[e] >> 32) < t) need |= (1u << e);
                if (!need) break;
                #pragma unroll
                for (int e = 0; e < 8; ++e)
                    if (need & (1u << e))
                        pv[e] = __hip_atomic_load((unsigned long long*)&hsp[e], RLX, AGENT);
            }
            #pragma unroll
            for (int e = 0; e < 8; ++e) tmph[e] = pk_val(pv[e]);
        }
        {
            bf16x8 hi, lo; split8(tmph, hi, lo);
            s_ga[0][4 + w][lane] = hi; s_ga[1][4 + w][lane] = lo;
        }
        __syncthreads();   // (2)

        #pragma unroll
        for (int j = 0; j < 4; ++j) {
            const int ks = 4 + kh * 4 + j;
            bf16x8 ah = s_ga[0][ks][lane], al = s_ga[1][ks][lane];
            ac0 = MFMA(ah, whh_hi[j], ac0);
            ac1 = MFMA(ah, whh_lo[j], ac1);
            ac2 = MFMA(al, whh_hi[j], ac2);
        }
        {
            f32x4 acc = ac0 + ac1 + ac2;
            *(f32x4*)&s_part[kh][g][lane][0] = acc;
        }
        __syncthreads();   // (3)

        if (tid < 256) {
            const int m = tid >> 4, ul = tid & 15;
            const int li = ((m >> 2) << 4) | ul, r = m & 3;
            float gv[4];
            #pragma unroll
            for (int g2 = 0; g2 < 4; ++g2)
                gv[g2] = s_part[0][g2][li][r] + s_part[1][g2][li][r]
                       + s_bias[g2 * 16 + ul];
            float si = 1.f / (1.f + expf(-gv[0]));
            float sf = 1.f / (1.f + expf(-gv[1]));
            float gt = tanhf(gv[2]);
            float so = 1.f / (1.f + expf(-gv[3]));
            c_reg = sf * c_reg + si * gt;
            float hn = so * tanhf(c_reg);
            __hip_atomic_store(&outp[(size_t)(row0 + m) * (Tn * Hn) + (size_t)t * Hn + u0 + ul],
                               hn, RLX, AGENT);
            if (t < Tn - 1) {
                float hin = hn;
                if (do_ring) {
                    float sk = 0.f;
                    #pragma unroll
                    for (int w2 = 0; w2 < 8; ++w2) sk += s_sk[w2][li][r];
                    hin += sk + s_bskip[ul];
                }
                __hip_atomic_store(&g_hxp[(t + 1) & 1][row0 + m][u0 + ul],
                                   pk_make(t + 1, hin), RLX, AGENT);
                s_hown[m][ul] = hin;
            } else {
                hbuf[(size_t)(row0 + m) * Hn + u0 + ul] = hn;
                cbuf[(size_t)(row0 + m) * Hn + u0 + ul] = c_reg;
            }
        }
    }
}

extern "C" void kernel_launch(void* const* d_in, const int* in_sizes, int n_in,
                              void* d_out, int out_size, void* d_ws, size_t ws_size,
                              hipStream_t stream)
{
    const float* x      = (const float*)d_in[0];
    const float* W_ih   = (const float*)d_in[1];
    const float* W_hh   = (const float*)d_in[2];
    const float* b_ih   = (const float*)d_in[3];
    const float* b_hh   = (const float*)d_in[4];
    const float* W_skip = (const float*)d_in[5];
    const float* b_skip = (const float*)d_in[6];
    const float* h0     = (const float*)d_in[7];
    const float* c0     = (const float*)d_in[8];

    float* outp = (float*)d_out;
    float* hbuf = outp + (size_t)Bn * Tn * Hn;
    float* cbuf = hbuf + (size_t)Bn * Hn;

    init_pack<<<256, 256, 0, stream>>>(h0);
    lstm_persist<<<256, 512, 40960, stream>>>(x, W_ih, W_hh, b_ih, b_hh,
                                              W_skip, b_skip, c0, outp, hbuf, cbuf);
}

// Round 8
// 3939.200 us; speedup vs baseline: 2.9243x; 2.9243x over previous
//
#include <hip/hip_runtime.h>
#include <cstddef>

#define Bn  256
#define Tn  1024
#define Cn  128
#define Hn  256
#define WIN 24

#define NRG 16
#define NUG 16
#define RPB 16
#define UPB 16

#define AGENT __HIP_MEMORY_SCOPE_AGENT
#define RLX   __ATOMIC_RELAXED

typedef __attribute__((ext_vector_type(8))) short bf16x8;
typedef __attribute__((ext_vector_type(4))) float f32x4;

#define MFMA(a, b, c) __builtin_amdgcn_mfma_f32_16x16x32_bf16((a), (b), (c), 0, 0, 0)

struct __align__(64) Flag { int v; int pad[15]; };
__device__ Flag  g_flag[NRG][NUG];
__device__ float g_hx[2][Bn][Hn];   // h_in exchange, double-buffered by t parity

__device__ inline unsigned short f2bf(float f) {
    union { float f; unsigned u; } v; v.f = f;
    unsigned r = (v.u + 0x7FFF + ((v.u >> 16) & 1)) >> 16;   // RNE
    return (unsigned short)r;
}
__device__ inline float bf2f(unsigned short b) {
    union { unsigned u; float f; } v; v.u = (unsigned)b << 16;
    return v.f;
}
__device__ inline void split8(const float* s, bf16x8& hi, bf16x8& lo) {
    #pragma unroll
    for (int e = 0; e < 8; ++e) {
        unsigned short h = f2bf(s[e]);
        float r = s[e] - bf2f(h);
        hi[e] = (short)h;
        lo[e] = (short)f2bf(r);
    }
}

__global__ __launch_bounds__(256) void init_sync(const float* __restrict__ h0) {
    int i = blockIdx.x * 256 + threadIdx.x;       // 0 .. 65535
    g_hx[0][i >> 8][i & 255] = h0[i & 255];       // h_in(0) = h0 (mask=0 at t=0)
    g_hx[1][i >> 8][i & 255] = 0.f;
    if (i < NRG * NUG) g_flag[i >> 4][i & 15].v = 0;
}

__global__ __launch_bounds__(512, 1) void lstm_persist(
    const float* __restrict__ x,
    const float* __restrict__ W_ih, const float* __restrict__ W_hh,
    const float* __restrict__ b_ih, const float* __restrict__ b_hh,
    const float* __restrict__ W_skip, const float* __restrict__ b_skip,
    const float* __restrict__ h0, const float* __restrict__ c0,
    float* __restrict__ outp, float* __restrict__ hbuf, float* __restrict__ cbuf)
{
    __shared__ bf16x8 s_ga[2][12][64];    // [hi/lo][kstep 0..3 x, 4..11 h][lane]
    __shared__ float  s_part[2][4][64][4];// [khalf][gate][lane][reg]
    __shared__ float  s_sk[8][64][4];     // skip partials per wave
    __shared__ float  s_hown[16][16];     // our own h_in slice
    __shared__ float  s_hout[16][16];     // h_new for outp batch store
    __shared__ float  s_bias[64];
    __shared__ float  s_bskip[UPB];
    __shared__ int    s_fl[16];           // sampled peer flags
    __shared__ float  s_pad[9664];        // STATIC pad: total 82048 B -> 1 block/CU

    const int tid = threadIdx.x;
    if (tid == 0) ((volatile float*)s_pad)[0] = 0.f;   // keep s_pad allocated

    // XCD swizzle (perf heuristic only; proven by r4's FETCH collapse)
    const int xcd = blockIdx.x & 7, slot = blockIdx.x >> 3;
    const int rg = (xcd << 1) | (slot >> 4), ug = slot & 15;
    const int row0 = rg * RPB, u0 = ug * UPB;

    const int w = tid >> 6, lane = tid & 63;
    const int g = w & 3, kh = w >> 2;
    const int nl = lane & 15, kq = lane >> 4;
    const int sm = lane & 15;                 // staged row
    const int k0 = w * 32 + kq * 8;           // staged unit-octet base
    const int peer = k0 >> 4;                 // unit group owning this octet
    const bool own = (peer == ug);
    const bool fw  = (w == 7) && (lane < 16); // flag-duty lanes

    // ---- once: B-operand weight fragments into registers (r5/r7-identical) ----
    bf16x8 whh_hi[4], whh_lo[4], wx_hi[2], wx_lo[2], ws_hi, ws_lo;
    {
        const int Rg = g * Hn + u0 + nl;
        const float* wr = W_hh + (size_t)Rg * Hn;
        #pragma unroll
        for (int j = 0; j < 4; ++j) {
            float tmp[8];
            const int k = (kh * 4 + j) * 32 + kq * 8;
            #pragma unroll
            for (int e = 0; e < 8; ++e) tmp[e] = wr[k + e];
            split8(tmp, whh_hi[j], whh_lo[j]);
        }
        const float* wr2 = W_ih + (size_t)Rg * Cn;
        #pragma unroll
        for (int j = 0; j < 2; ++j) {
            float tmp[8];
            const int k = (kh * 2 + j) * 32 + kq * 8;
            #pragma unroll
            for (int e = 0; e < 8; ++e) tmp[e] = wr2[k + e];
            split8(tmp, wx_hi[j], wx_lo[j]);
        }
        const float* wr3 = W_skip + (size_t)(u0 + nl) * Hn;
        float tmp[8];
        const int k = w * 32 + kq * 8;
        #pragma unroll
        for (int e = 0; e < 8; ++e) tmp[e] = wr3[k + e];
        split8(tmp, ws_hi, ws_lo);
    }
    if (tid < 64)  s_bias[tid]  = b_ih[(tid >> 4) * Hn + u0 + (tid & 15)]
                                + b_hh[(tid >> 4) * Hn + u0 + (tid & 15)];
    if (tid < 16)  s_bskip[tid] = b_skip[u0 + tid];

    float c_reg = 0.f;
    if (tid < 256) c_reg = c0[u0 + (tid & 15)];
    if (tid < 256) s_hown[tid >> 4][tid & 15] = h0[u0 + (tid & 15)];

    f32x4 ring_a = {0.f,0.f,0.f,0.f}, ring_b = {0.f,0.f,0.f,0.f};
    __syncthreads();

    for (int t = 0; t < Tn; ++t) {
        const bool do_ring = (t >= WIN - 1) && (t < Tn - 1);   // skip active this step
        const bool nr      = (t >= WIN - 2) && (t < Tn - 2);   // prefetch for t+1

        // ================= PHASE A (no h_t dependency) =================
        // A0: sample all 16 peer flags (one waited MALL load, wave-7 lanes)
        int f_s = 0;
        if (fw) f_s = __hip_atomic_load(&g_flag[rg][lane].v, RLX, AGENT);

        // A1: skip-GEMM directly from ring prefetch registers (loaded at t-1;
        //     drained by last step's publish vmcnt(0), so the wait is ~free)
        if (do_ring) {
            asm volatile("s_waitcnt vmcnt(0)" : "+v"(ring_a), "+v"(ring_b) :: "memory");
            float rvv[8];
            #pragma unroll
            for (int e = 0; e < 4; ++e) { rvv[e] = ring_a[e]; rvv[4 + e] = ring_b[e]; }
            bf16x8 hi, lo; split8(rvv, hi, lo);
            f32x4 sk0 = {0.f,0.f,0.f,0.f}, sk1 = {0.f,0.f,0.f,0.f}, sk2 = {0.f,0.f,0.f,0.f};
            sk0 = MFMA(hi, ws_hi, sk0);
            sk1 = MFMA(hi, ws_lo, sk1);
            sk2 = MFMA(lo, ws_hi, sk2);
            *(f32x4*)&s_sk[w][lane][0] = sk0 + sk1 + sk2;
        }

        // A2: stage x_t fragments (plain loads; L2-dedup via XCD swizzle)
        if (tid < 256) {
            const int ksx = tid >> 6, lx = tid & 63;
            const int mx = lx & 15, kqx = lx >> 4;
            const float* src = x + (size_t)(row0 + mx) * (Tn * Cn) + (size_t)t * Cn
                                 + ksx * 32 + kqx * 8;
            float tmp[8];
            #pragma unroll
            for (int e = 0; e < 8; ++e) tmp[e] = src[e];
            bf16x8 hi, lo; split8(tmp, hi, lo);
            s_ga[0][ksx][lx] = hi; s_ga[1][ksx][lx] = lo;
        }
        if (fw) s_fl[lane] = f_s;
        __syncthreads();   // (1)

        // A3: speculative h-load for peers already at flag >= t (overlaps MFMA-x)
        const float* hsrc = &g_hx[t & 1][row0 + sm][k0];
        f32x4 ha = {0.f,0.f,0.f,0.f}, hb = {0.f,0.f,0.f,0.f};
        bool ready = false;
        if (!own && s_fl[peer] >= t) {
            ready = true;
            asm volatile("global_load_dwordx4 %0, %2, off sc0 sc1\n\t"
                         "global_load_dwordx4 %1, %2, off offset:16 sc0 sc1"
                         : "=&v"(ha), "=&v"(hb) : "v"(hsrc) : "memory");
        }

        // A4: x-part MFMA (3 independent chains)
        f32x4 ac0 = {0.f,0.f,0.f,0.f}, ac1 = {0.f,0.f,0.f,0.f}, ac2 = {0.f,0.f,0.f,0.f};
        #pragma unroll
        for (int j = 0; j < 2; ++j) {
            const int ks = kh * 2 + j;
            bf16x8 ah = s_ga[0][ks][lane], al = s_ga[1][ks][lane];
            ac0 = MFMA(ah, wx_hi[j], ac0);
            ac1 = MFMA(ah, wx_lo[j], ac1);
            ac2 = MFMA(al, wx_hi[j], ac2);
        }

        // A5: stage own slice (LDS) and ready-peer octets (spec loads)
        if (own) {
            float tmp[8];
            #pragma unroll
            for (int e = 0; e < 8; ++e) tmp[e] = s_hown[sm][(k0 & 15) + e];
            bf16x8 hi, lo; split8(tmp, hi, lo);
            s_ga[0][4 + w][lane] = hi; s_ga[1][4 + w][lane] = lo;
        } else if (ready) {
            asm volatile("s_waitcnt vmcnt(0)" : "+v"(ha), "+v"(hb) :: "memory");
            float tmp[8];
            #pragma unroll
            for (int e = 0; e < 4; ++e) { tmp[e] = ha[e]; tmp[4 + e] = hb[e]; }
            bf16x8 hi, lo; split8(tmp, hi, lo);
            s_ga[0][4 + w][lane] = hi; s_ga[1][4 + w][lane] = lo;
        }

        // ================= PHASE B (critical path) =================
        // B1: poll only straggler flags (16 addresses max, wave-7 lanes)
        if (fw && f_s < t) {
            int f = f_s;
            while (f < t) f = __hip_atomic_load(&g_flag[rg][lane].v, RLX, AGENT);
        }
        __syncthreads();   // (2)

        // B2: load octets whose peer was not ready at sample time
        if (!own && !ready) {
            f32x4 pa, pb;
            asm volatile("global_load_dwordx4 %0, %2, off sc0 sc1\n\t"
                         "global_load_dwordx4 %1, %2, off offset:16 sc0 sc1\n\t"
                         "s_waitcnt vmcnt(0)"
                         : "=&v"(pa), "=&v"(pb) : "v"(hsrc) : "memory");
            float tmp[8];
            #pragma unroll
            for (int e = 0; e < 4; ++e) { tmp[e] = pa[e]; tmp[4 + e] = pb[e]; }
            bf16x8 hi, lo; split8(tmp, hi, lo);
            s_ga[0][4 + w][lane] = hi; s_ga[1][4 + w][lane] = lo;
        }
        __syncthreads();   // (3)

        // B3: issue ring prefetch for t+1 (h(t-22); consumed next step)
        if (nr) {
            const float* rsrc = outp + (size_t)(row0 + sm) * (Tn * Hn)
                                     + (size_t)(t - (WIN - 2)) * Hn + k0;
            asm volatile("global_load_dwordx4 %0, %2, off sc0 sc1\n\t"
                         "global_load_dwordx4 %1, %2, off offset:16 sc0 sc1"
                         : "=&v"(ring_a), "=&v"(ring_b) : "v"(rsrc) : "memory");
        }

        // B4: h-part MFMA (3 independent chains)
        #pragma unroll
        for (int j = 0; j < 4; ++j) {
            const int ks = 4 + kh * 4 + j;
            bf16x8 ah = s_ga[0][ks][lane], al = s_ga[1][ks][lane];
            ac0 = MFMA(ah, whh_hi[j], ac0);
            ac1 = MFMA(ah, whh_lo[j], ac1);
            ac2 = MFMA(al, whh_hi[j], ac2);
        }
        {
            f32x4 acc = ac0 + ac1 + ac2;
            *(f32x4*)&s_part[kh][g][lane][0] = acc;
        }
        __syncthreads();   // (4)

        // B5: cell update; thread tid<256 owns (row m, unit ul)
        if (tid < 256) {
            const int m = tid >> 4, ul = tid & 15;
            const int li = ((m >> 2) << 4) | ul, r = m & 3;
            float gv[4];
            #pragma unroll
            for (int g2 = 0; g2 < 4; ++g2)
                gv[g2] = s_part[0][g2][li][r] + s_part[1][g2][li][r]
                       + s_bias[g2 * 16 + ul];
            float si = 1.f / (1.f + expf(-gv[0]));
            float sf = 1.f / (1.f + expf(-gv[1]));
            float gt = tanhf(gv[2]);
            float so = 1.f / (1.f + expf(-gv[3]));
            c_reg = sf * c_reg + si * gt;
            float hn = so * tanhf(c_reg);
            s_hout[m][ul] = hn;
            if (t < Tn - 1) {
                float hin = hn;
                if (do_ring) {
                    float sk = 0.f;
                    #pragma unroll
                    for (int w2 = 0; w2 < 8; ++w2) sk += s_sk[w2][li][r];
                    hin += sk + s_bskip[ul];
                }
                s_hown[m][ul] = hin;
            } else {
                hbuf[(size_t)(row0 + m) * Hn + u0 + ul] = hn;
                cbuf[(size_t)(row0 + m) * Hn + u0 + ul] = c_reg;
            }
        }
        __syncthreads();   // (5)

        // B6: batched 16B publishes (64 hx stores + 64 outp stores per block)
        if (tid < 64) {
            if (t < Tn - 1) {
                const int r8 = tid >> 2, q = tid & 3;
                f32x4 v = *(const f32x4*)&s_hown[r8][q * 4];
                float* dst = &g_hx[(t + 1) & 1][row0 + r8][u0 + q * 4];
                asm volatile("global_store_dwordx4 %0, %1, off sc0 sc1"
                             :: "v"(dst), "v"(v) : "memory");
            }
        } else if (tid < 128) {
            const int r8 = (tid - 64) >> 2, q = (tid - 64) & 3;
            f32x4 v = *(const f32x4*)&s_hout[r8][q * 4];
            float* dst = &outp[(size_t)(row0 + r8) * (Tn * Hn) + (size_t)t * Hn + u0 + q * 4];
            asm volatile("global_store_dwordx4 %0, %1, off sc0 sc1"
                         :: "v"(dst), "v"(v) : "memory");
        }
        // B7: drain to coherence point, then release flag
        if (t < Tn - 1) {
            asm volatile("s_waitcnt vmcnt(0)" ::: "memory");
            __syncthreads();   // (6)
            if (tid == 0)
                __hip_atomic_store(&g_flag[rg][ug].v, t + 1, RLX, AGENT);
        }
    }
}

extern "C" void kernel_launch(void* const* d_in, const int* in_sizes, int n_in,
                              void* d_out, int out_size, void* d_ws, size_t ws_size,
                              hipStream_t stream)
{
    const float* x      = (const float*)d_in[0];
    const float* W_ih   = (const float*)d_in[1];
    const float* W_hh   = (const float*)d_in[2];
    const float* b_ih   = (const float*)d_in[3];
    const float* b_hh   = (const float*)d_in[4];
    const float* W_skip = (const float*)d_in[5];
    const float* b_skip = (const float*)d_in[6];
    const float* h0     = (const float*)d_in[7];
    const float* c0     = (const float*)d_in[8];

    float* outp = (float*)d_out;
    float* hbuf = outp + (size_t)Bn * Tn * Hn;
    float* cbuf = hbuf + (size_t)Bn * Hn;

    init_sync<<<256, 256, 0, stream>>>(h0);
    lstm_persist<<<256, 512, 0, stream>>>(x, W_ih, W_hh, b_ih, b_hh,
                                          W_skip, b_skip, h0, c0, outp, hbuf, cbuf);
}

// Round 9
// 3393.229 us; speedup vs baseline: 3.3948x; 1.1609x over previous
//
#include <hip/hip_runtime.h>
#include <cstddef>
#include <cmath>

#define Bn  256
#define Tn  1024
#define Cn  128
#define Hn  256
#define WIN 24

#define NRG 16
#define NUG 16
#define RPB 16
#define UPB 16

#define AGENT __HIP_MEMORY_SCOPE_AGENT
#define RLX   __ATOMIC_RELAXED

typedef __attribute__((ext_vector_type(8))) short bf16x8;
typedef __attribute__((ext_vector_type(4))) float f32x4;
typedef __attribute__((ext_vector_type(4))) unsigned int u32x4;

#define MFMA(a, b, c) __builtin_amdgcn_mfma_f32_16x16x32_bf16((a), (b), (c), 0, 0, 0)

struct __align__(64) Flag { int v; int pad[15]; };
__device__ Flag g_flag[NRG][NUG];
// h_in exchange as PRE-SPLIT bf16 planes (exactly what MFMA consumes; same
// total bytes as fp32, zero consumer-side conversion). Double-buffered by parity.
__device__ unsigned short g_hx_hi[2][Bn][Hn];
__device__ unsigned short g_hx_lo[2][Bn][Hn];

__device__ inline unsigned short f2bf(float f) {
    union { float f; unsigned u; } v; v.f = f;
    unsigned r = (v.u + 0x7FFF + ((v.u >> 16) & 1)) >> 16;   // RNE
    return (unsigned short)r;
}
__device__ inline float bf2f(unsigned short b) {
    union { unsigned u; float f; } v; v.u = (unsigned)b << 16;
    return v.f;
}
__device__ inline void split8(const float* s, bf16x8& hi, bf16x8& lo) {
    #pragma unroll
    for (int e = 0; e < 8; ++e) {
        unsigned short h = f2bf(s[e]);
        float r = s[e] - bf2f(h);
        hi[e] = (short)h;
        lo[e] = (short)f2bf(r);
    }
}
// fast activations: v_exp_f32 (exp2) + v_rcp_f32; NaN-free for finite gates
__device__ inline float fsigm(float x) {
    return __builtin_amdgcn_rcpf(1.f + exp2f(x * -1.442695041f));
}
__device__ inline float ftanh(float x) {
    return 1.f - 2.f * __builtin_amdgcn_rcpf(1.f + exp2f(x * 2.885390082f));
}

__global__ __launch_bounds__(256) void init_sync(const float* __restrict__ h0) {
    int i = blockIdx.x * 256 + threadIdx.x;       // 0 .. 65535
    int b = i >> 8, u = i & 255;
    float hv = h0[u];                              // h_in(0) = h0 (mask=0 at t=0)
    unsigned short hi = f2bf(hv);
    g_hx_hi[0][b][u] = hi;
    g_hx_lo[0][b][u] = f2bf(hv - bf2f(hi));
    g_hx_hi[1][b][u] = 0;
    g_hx_lo[1][b][u] = 0;
    if (i < NRG * NUG) g_flag[i >> 4][i & 15].v = 0;
}

__global__ __launch_bounds__(512, 1) void lstm_persist(
    const float* __restrict__ x,
    const float* __restrict__ W_ih, const float* __restrict__ W_hh,
    const float* __restrict__ b_ih, const float* __restrict__ b_hh,
    const float* __restrict__ W_skip, const float* __restrict__ b_skip,
    const float* __restrict__ h0, const float* __restrict__ c0,
    float* __restrict__ outp, float* __restrict__ hbuf, float* __restrict__ cbuf)
{
    __shared__ bf16x8 s_ga[2][12][64];     // [hi/lo][kstep 0..3 x, 4..11 h][lane]
    __shared__ float  s_part[2][4][64][4]; // [khalf][gate][lane][reg]
    __shared__ float  s_sk[8][64][4];      // skip partials per wave
    __shared__ __align__(16) unsigned short s_hown_hi[16][16];  // own h_in, split planes
    __shared__ __align__(16) unsigned short s_hown_lo[16][16];
    __shared__ float  s_hout[16][16];      // h_new for outp batch store
    __shared__ float  s_bias[64];
    __shared__ float  s_bskip[UPB];
    __shared__ int    s_fl[16];            // sampled peer flags
    __shared__ float  s_pad[9700];         // pad: total >80KB -> 1 block/CU

    const int tid = threadIdx.x;
    if (tid == 0) ((volatile float*)s_pad)[0] = 0.f;   // keep s_pad allocated

    // XCD swizzle (perf heuristic; proven by r4's FETCH collapse)
    const int xcd = blockIdx.x & 7, slot = blockIdx.x >> 3;
    const int rg = (xcd << 1) | (slot >> 4), ug = slot & 15;
    const int row0 = rg * RPB, u0 = ug * UPB;

    const int w = tid >> 6, lane = tid & 63;
    const int g = w & 3, kh = w >> 2;
    const int nl = lane & 15, kq = lane >> 4;
    const int sm = lane & 15;                 // staged row
    const int k0 = w * 32 + kq * 8;           // staged unit-octet base
    const int peer = k0 >> 4;                 // unit group owning this octet
    const bool own = (peer == ug);
    const bool fw  = (w == 7) && (lane < 16); // flag-duty lanes
    // x(t+1) staging role (waves 4-7)
    const int ksx2 = (tid >> 6) - 4, lx2 = tid & 63;
    const int mx2 = lx2 & 15, kqx2 = lx2 >> 4;

    // ---- once: B-operand weight fragments into registers (r5/r8-identical) ----
    bf16x8 whh_hi[4], whh_lo[4], wx_hi[2], wx_lo[2], ws_hi, ws_lo;
    {
        const int Rg = g * Hn + u0 + nl;
        const float* wr = W_hh + (size_t)Rg * Hn;
        #pragma unroll
        for (int j = 0; j < 4; ++j) {
            float tmp[8];
            const int k = (kh * 4 + j) * 32 + kq * 8;
            #pragma unroll
            for (int e = 0; e < 8; ++e) tmp[e] = wr[k + e];
            split8(tmp, whh_hi[j], whh_lo[j]);
        }
        const float* wr2 = W_ih + (size_t)Rg * Cn;
        #pragma unroll
        for (int j = 0; j < 2; ++j) {
            float tmp[8];
            const int k = (kh * 2 + j) * 32 + kq * 8;
            #pragma unroll
            for (int e = 0; e < 8; ++e) tmp[e] = wr2[k + e];
            split8(tmp, wx_hi[j], wx_lo[j]);
        }
        const float* wr3 = W_skip + (size_t)(u0 + nl) * Hn;
        float tmp[8];
        const int k = w * 32 + kq * 8;
        #pragma unroll
        for (int e = 0; e < 8; ++e) tmp[e] = wr3[k + e];
        split8(tmp, ws_hi, ws_lo);
    }
    if (tid < 64)  s_bias[tid]  = b_ih[(tid >> 4) * Hn + u0 + (tid & 15)]
                                + b_hh[(tid >> 4) * Hn + u0 + (tid & 15)];
    if (tid < 16)  s_bskip[tid] = b_skip[u0 + tid];

    float c_reg = 0.f;
    if (tid < 256) c_reg = c0[u0 + (tid & 15)];
    if (tid < 256) {
        float hv = h0[u0 + (tid & 15)];
        unsigned short phi = f2bf(hv);
        s_hown_hi[tid >> 4][tid & 15] = phi;
        s_hown_lo[tid >> 4][tid & 15] = f2bf(hv - bf2f(phi));
    }
    // pre-loop: stage x(0) fragments
    if (tid < 256) {
        const int ksx = tid >> 6, lx = tid & 63;
        const int mx = lx & 15, kqx = lx >> 4;
        const float* src = x + (size_t)(row0 + mx) * (Tn * Cn) + ksx * 32 + kqx * 8;
        float tmp[8];
        #pragma unroll
        for (int e = 0; e < 8; ++e) tmp[e] = src[e];
        bf16x8 hi, lo; split8(tmp, hi, lo);
        s_ga[0][ksx][lx] = hi; s_ga[1][ksx][lx] = lo;
    }
    f32x4 ring_a = {0.f,0.f,0.f,0.f}, ring_b = {0.f,0.f,0.f,0.f};
    __syncthreads();

    for (int t = 0; t < Tn; ++t) {
        const bool do_ring = (t >= WIN - 1) && (t < Tn - 1);   // skip active this step
        const bool nr      = (t >= WIN - 2) && (t < Tn - 2);   // ring prefetch for t+1

        // ================= PHASE A (no h_t dependency) =================
        // A0: sample all 16 peer flags (wave-7 lanes)
        int f_s = 0;
        if (fw) f_s = __hip_atomic_load(&g_flag[rg][lane].v, RLX, AGENT);

        // A1: skip-GEMM from ring prefetch regs (issued at end of t-1)
        if (do_ring) {
            asm volatile("s_waitcnt vmcnt(0)" : "+v"(ring_a), "+v"(ring_b) :: "memory");
            float rvv[8];
            #pragma unroll
            for (int e = 0; e < 4; ++e) { rvv[e] = ring_a[e]; rvv[4 + e] = ring_b[e]; }
            bf16x8 hi, lo; split8(rvv, hi, lo);
            f32x4 sk0 = {0.f,0.f,0.f,0.f}, sk1 = {0.f,0.f,0.f,0.f}, sk2 = {0.f,0.f,0.f,0.f};
            sk0 = MFMA(hi, ws_hi, sk0);
            sk1 = MFMA(hi, ws_lo, sk1);
            sk2 = MFMA(lo, ws_hi, sk2);
            *(f32x4*)&s_sk[w][lane][0] = sk0 + sk1 + sk2;
        }
        if (fw) s_fl[lane] = f_s;
        __syncthreads();   // (1)

        // A3: spec round 1 — peers already at flag >= t (overlaps x-MFMA)
        const unsigned short* hip_ = &g_hx_hi[t & 1][row0 + sm][k0];
        const unsigned short* lop_ = &g_hx_lo[t & 1][row0 + sm][k0];
        bf16x8 ha, hb;
        bool ready = false;
        if (!own && s_fl[peer] >= t) {
            ready = true;
            asm volatile("global_load_dwordx4 %0, %2, off sc0 sc1\n\t"
                         "global_load_dwordx4 %1, %3, off sc0 sc1"
                         : "=&v"(ha), "=&v"(hb) : "v"(hip_), "v"(lop_) : "memory");
        }

        // A4: x-part MFMA (3 independent chains)
        f32x4 ac0 = {0.f,0.f,0.f,0.f}, ac1 = {0.f,0.f,0.f,0.f}, ac2 = {0.f,0.f,0.f,0.f};
        #pragma unroll
        for (int j = 0; j < 2; ++j) {
            const int ks = kh * 2 + j;
            bf16x8 ah = s_ga[0][ks][lane], al = s_ga[1][ks][lane];
            ac0 = MFMA(ah, wx_hi[j], ac0);
            ac1 = MFMA(ah, wx_lo[j], ac1);
            ac2 = MFMA(al, wx_hi[j], ac2);
        }

        // A6: spec round 2 — re-check own peer (catches flags that arrived in A)
        if (!own && !ready) {
            int f2 = __hip_atomic_load(&g_flag[rg][peer].v, RLX, AGENT);
            if (f2 >= t) {
                ready = true;
                asm volatile("global_load_dwordx4 %0, %2, off sc0 sc1\n\t"
                             "global_load_dwordx4 %1, %3, off sc0 sc1"
                             : "=&v"(ha), "=&v"(hb) : "v"(hip_), "v"(lop_) : "memory");
            }
        }

        // ================= PHASE B (critical path) =================
        // B1: poll only straggler flags
        if (fw && f_s < t) {
            int f = f_s;
            while (f < t) f = __hip_atomic_load(&g_flag[rg][lane].v, RLX, AGENT);
        }
        __syncthreads();   // (2)

        // B2: stage h fragments (zero conversion — planes are already bf16 hi/lo)
        if (own) {
            bf16x8 hi8 = *(const bf16x8*)&s_hown_hi[sm][k0 & 15];
            bf16x8 lo8 = *(const bf16x8*)&s_hown_lo[sm][k0 & 15];
            s_ga[0][4 + w][lane] = hi8;
            s_ga[1][4 + w][lane] = lo8;
        } else {
            if (!ready) {
                asm volatile("global_load_dwordx4 %0, %2, off sc0 sc1\n\t"
                             "global_load_dwordx4 %1, %3, off sc0 sc1"
                             : "=&v"(ha), "=&v"(hb) : "v"(hip_), "v"(lop_) : "memory");
            }
            asm volatile("s_waitcnt vmcnt(0)" : "+v"(ha), "+v"(hb) :: "memory");
            s_ga[0][4 + w][lane] = ha;
            s_ga[1][4 + w][lane] = hb;
        }
        __syncthreads();   // (3)

        // B4: issue x(t+1) loads (waves 4-7, consumed in B5 window), then h-MFMA
        f32x4 xa, xb;
        const bool xst = (tid >= 256) && (t + 1 < Tn);
        if (xst) {
            const float* xsrc = x + (size_t)(row0 + mx2) * (Tn * Cn)
                                  + (size_t)(t + 1) * Cn + ksx2 * 32 + kqx2 * 8;
            xa = *(const f32x4*)xsrc;
            xb = *(const f32x4*)(xsrc + 4);
        }
        #pragma unroll
        for (int j = 0; j < 4; ++j) {
            const int ks = 4 + kh * 4 + j;
            bf16x8 ah = s_ga[0][ks][lane], al = s_ga[1][ks][lane];
            ac0 = MFMA(ah, whh_hi[j], ac0);
            ac1 = MFMA(ah, whh_lo[j], ac1);
            ac2 = MFMA(al, whh_hi[j], ac2);
        }
        {
            f32x4 acc = ac0 + ac1 + ac2;
            *(f32x4*)&s_part[kh][g][lane][0] = acc;
        }
        __syncthreads();   // (4)

        // B5: cell update (waves 0-3) || x(t+1) staging (waves 4-7)
        if (tid < 256) {
            const int m = tid >> 4, ul = tid & 15;
            const int li = ((m >> 2) << 4) | ul, r = m & 3;
            float gv[4];
            #pragma unroll
            for (int g2 = 0; g2 < 4; ++g2)
                gv[g2] = s_part[0][g2][li][r] + s_part[1][g2][li][r]
                       + s_bias[g2 * 16 + ul];
            float si = fsigm(gv[0]);
            float sf = fsigm(gv[1]);
            float gt = ftanh(gv[2]);
            float so = fsigm(gv[3]);
            c_reg = sf * c_reg + si * gt;
            float hn = so * ftanh(c_reg);
            s_hout[m][ul] = hn;
            if (t < Tn - 1) {
                float hin = hn;
                if (do_ring) {
                    float sk = 0.f;
                    #pragma unroll
                    for (int w2 = 0; w2 < 8; ++w2) sk += s_sk[w2][li][r];
                    hin += sk + s_bskip[ul];
                }
                unsigned short phi = f2bf(hin);
                s_hown_hi[m][ul] = phi;
                s_hown_lo[m][ul] = f2bf(hin - bf2f(phi));
            } else {
                hbuf[(size_t)(row0 + m) * Hn + u0 + ul] = hn;
                cbuf[(size_t)(row0 + m) * Hn + u0 + ul] = c_reg;
            }
        } else if (xst) {
            float tmp[8];
            #pragma unroll
            for (int e = 0; e < 4; ++e) { tmp[e] = xa[e]; tmp[4 + e] = xb[e]; }
            bf16x8 hi, lo; split8(tmp, hi, lo);
            s_ga[0][ksx2][lx2] = hi;
            s_ga[1][ksx2][lx2] = lo;
        }
        __syncthreads();   // (5)

        // B6: batched 16B publishes (hx planes + outp)
        if (t < Tn - 1) {
            if (tid < 32) {
                const int r8_ = tid >> 1, hf = tid & 1;
                u32x4 v = *(const u32x4*)&s_hown_hi[r8_][hf * 8];
                unsigned short* dst = &g_hx_hi[(t + 1) & 1][row0 + r8_][u0 + hf * 8];
                asm volatile("global_store_dwordx4 %0, %1, off sc0 sc1"
                             :: "v"(dst), "v"(v) : "memory");
            } else if (tid < 64) {
                const int r8_ = (tid - 32) >> 1, hf = tid & 1;
                u32x4 v = *(const u32x4*)&s_hown_lo[r8_][hf * 8];
                unsigned short* dst = &g_hx_lo[(t + 1) & 1][row0 + r8_][u0 + hf * 8];
                asm volatile("global_store_dwordx4 %0, %1, off sc0 sc1"
                             :: "v"(dst), "v"(v) : "memory");
            }
        }
        if (tid >= 64 && tid < 128) {
            const int r8_ = (tid - 64) >> 2, q = (tid - 64) & 3;
            f32x4 v = *(const f32x4*)&s_hout[r8_][q * 4];
            float* dst = &outp[(size_t)(row0 + r8_) * (Tn * Hn) + (size_t)t * Hn + u0 + q * 4];
            asm volatile("global_store_dwordx4 %0, %1, off sc0 sc1"
                         :: "v"(dst), "v"(v) : "memory");
        }
        // B7: drain publishes only (ring NOT yet issued), then flag, THEN ring
        asm volatile("s_waitcnt vmcnt(0)" ::: "memory");
        __syncthreads();   // (6)
        if (t < Tn - 1) {
            if (tid == 0)
                __hip_atomic_store(&g_flag[rg][ug].v, t + 1, RLX, AGENT);
        }
        // ring prefetch for t+1 (h(t-22)); in flight across the step boundary
        if (nr) {
            const float* rsrc = outp + (size_t)(row0 + sm) * (Tn * Hn)
                                     + (size_t)(t - (WIN - 2)) * Hn + k0;
            asm volatile("global_load_dwordx4 %0, %2, off sc0 sc1\n\t"
                         "global_load_dwordx4 %1, %2, off offset:16 sc0 sc1"
                         : "=&v"(ring_a), "=&v"(ring_b) : "v"(rsrc) : "memory");
        }
    }
}

extern "C" void kernel_launch(void* const* d_in, const int* in_sizes, int n_in,
                              void* d_out, int out_size, void* d_ws, size_t ws_size,
                              hipStream_t stream)
{
    const float* x      = (const float*)d_in[0];
    const float* W_ih   = (const float*)d_in[1];
    const float* W_hh   = (const float*)d_in[2];
    const float* b_ih   = (const float*)d_in[3];
    const float* b_hh   = (const float*)d_in[4];
    const float* W_skip = (const float*)d_in[5];
    const float* b_skip = (const float*)d_in[6];
    const float* h0     = (const float*)d_in[7];
    const float* c0     = (const float*)d_in[8];

    float* outp = (float*)d_out;
    float* hbuf = outp + (size_t)Bn * Tn * Hn;
    float* cbuf = hbuf + (size_t)Bn * Hn;

    init_sync<<<256, 256, 0, stream>>>(h0);
    lstm_persist<<<256, 512, 0, stream>>>(x, W_ih, W_hh, b_ih, b_hh,
                                          W_skip, b_skip, h0, c0, outp, hbuf, cbuf);
}